// Round 12
// baseline (197.997 us; speedup 1.0000x reference)
//
#include <hip/hip_runtime.h>
#include <hip/hip_bf16.h>

typedef __hip_bfloat16 bf16;
typedef __attribute__((ext_vector_type(8))) short short8_t;
typedef __attribute__((ext_vector_type(4))) short short4_t;
typedef __attribute__((ext_vector_type(4))) float f32x4;

#define B_SZ   2
#define T_SEQ  2048
#define C_DIM  1024
#define NH     16
#define NKV    4
#define HD     64
#define QKVW   1536          // fused QKV row width (1024 Q | 256 K | 256 V)
#define MTOK   (B_SZ * T_SEQ)

#define LOG2_BASE_OVER_32 0.4152410118609203f
#define Q_SCALE 0.1803368801111204f   // 0.125 * log2(e)

__device__ __forceinline__ short f2bs(float f) {
    unsigned u = __float_as_uint(f);
    u += 0x7FFFu + ((u >> 16) & 1u);
    return (short)(u >> 16);
}
__device__ __forceinline__ short f2bs_trunc(float f) {
    return (short)(__float_as_uint(f) >> 16);
}
__device__ __forceinline__ float bs2f(short s) {
    unsigned u = ((unsigned)(unsigned short)s) << 16;
    return __uint_as_float(u);
}
// lane <-> lane^1 exchange, pure VALU (quad_perm [1,0,3,2])
__device__ __forceinline__ float dpp_xor1(float x) {
    return __int_as_float(
        __builtin_amdgcn_update_dpp(0, __float_as_int(x), 0xB1, 0xF, 0xF, true));
}

// ---------------------------------------------------------------------------
// Fused prep (unchanged): x->bf16, weight transposes, bias concat, RoPE table
// ---------------------------------------------------------------------------
__device__ __forceinline__ void transpose_tile(
    const float* __restrict__ W, short* __restrict__ Wt,
    int K, int N, int n0, int k0, int tid)
{
    __shared__ float tile[32][33];
    int tx = tid & 31, ty = tid >> 5;
    #pragma unroll
    for (int i = 0; i < 4; ++i)
        tile[ty + 8 * i][tx] = W[(size_t)(k0 + ty + 8 * i) * N + n0 + tx];
    __syncthreads();
    #pragma unroll
    for (int i = 0; i < 4; ++i)
        Wt[(size_t)(n0 + ty + 8 * i) * K + k0 + tx] = f2bs(tile[tx][ty + 8 * i]);
}

__global__ __launch_bounds__(256) void prep_kernel(
    const float* __restrict__ x,
    const float* __restrict__ w_q, const float* __restrict__ w_k,
    const float* __restrict__ w_v, const float* __restrict__ w_o,
    const float* __restrict__ b_q, const float* __restrict__ b_k,
    const float* __restrict__ b_v,
    short* __restrict__ Xb, short* __restrict__ Wqkv, short* __restrict__ Wto,
    float* __restrict__ Bqkv, float2* __restrict__ Tab)
{
    int blk = blockIdx.x, tid = threadIdx.x;
    if (blk < 4096) {
        int i = blk * 1024 + tid * 4;
        float4 v = *(const float4*)(x + i);
        short4_t o;
        o[0] = f2bs(v.x); o[1] = f2bs(v.y); o[2] = f2bs(v.z); o[3] = f2bs(v.w);
        *(short4_t*)(Xb + i) = o;
    } else if (blk < 5120) {
        int l = blk - 4096;
        transpose_tile(w_q, Wqkv, C_DIM, C_DIM, (l & 31) * 32, (l >> 5) * 32, tid);
    } else if (blk < 5376) {
        int l = blk - 5120;
        transpose_tile(w_k, Wqkv + (size_t)1024 * C_DIM, C_DIM, 256,
                       (l & 7) * 32, (l >> 3) * 32, tid);
    } else if (blk < 5632) {
        int l = blk - 5376;
        transpose_tile(w_v, Wqkv + (size_t)1280 * C_DIM, C_DIM, 256,
                       (l & 7) * 32, (l >> 3) * 32, tid);
    } else if (blk < 6656) {
        int l = blk - 5632;
        transpose_tile(w_o, Wto, C_DIM, C_DIM, (l & 31) * 32, (l >> 5) * 32, tid);
    } else if (blk < 6662) {
        int i = (blk - 6656) * 256 + tid;
        float v;
        if (i < 1024)      v = b_q[i];
        else if (i < 1280) v = b_k[i - 1024];
        else               v = b_v[i - 1280];
        Bqkv[i] = v;
    } else {
        int idx = (blk - 6662) * 256 + tid;
        int t = idx >> 5, i = idx & 31;
        float ang = (float)t * exp2f(-(float)i * LOG2_BASE_OVER_32);
        Tab[idx] = make_float2(cosf(ang), sinf(ang));
    }
}

// ---------------------------------------------------------------------------
// QKV GEMM with fused epilogue (unchanged from round 11): Q roped+scaled,
// K roped, V transposed into Vt[d][token].
// ---------------------------------------------------------------------------
__global__ __launch_bounds__(256) void gemm_qkv(
    const short* __restrict__ A, const short* __restrict__ Bt,
    const float* __restrict__ bias, const float2* __restrict__ Tab,
    short* __restrict__ QKVb, short* __restrict__ Vt)
{
    __shared__ __align__(16) short smem[20480];          // 40 KB
    typedef short lds_tile_t[128][40];
    lds_tile_t* sA = (lds_tile_t*)smem;
    lds_tile_t* sB = (lds_tile_t*)(smem + 10240);

    const int K = C_DIM;
    int m0 = blockIdx.y * 128;
    int n0 = blockIdx.x * 128;
    int tid  = threadIdx.x;
    int w    = tid >> 6, lane = tid & 63;
    int quad = lane >> 4, l16 = lane & 15;
    int wm = w & 1, wn = w >> 1;

    f32x4 acc[4][4] = {};

    short8_t ra[2], rb[2];
    #pragma unroll
    for (int it = 0; it < 2; ++it) {
        int slot = tid + 256 * it, row = slot >> 2, g = (slot & 3) * 8;
        ra[it] = *(const short8_t*)(A  + (size_t)(m0 + row) * K + g);
        rb[it] = *(const short8_t*)(Bt + (size_t)(n0 + row) * K + g);
    }

    int buf = 0;
    for (int k0 = 0; k0 < K; k0 += 32, buf ^= 1) {
        #pragma unroll
        for (int it = 0; it < 2; ++it) {
            int slot = tid + 256 * it, row = slot >> 2, g = (slot & 3) * 8;
            *(short8_t*)&sA[buf][row][g] = ra[it];
            *(short8_t*)&sB[buf][row][g] = rb[it];
        }
        if (k0 + 32 < K) {
            #pragma unroll
            for (int it = 0; it < 2; ++it) {
                int slot = tid + 256 * it, row = slot >> 2, g = (slot & 3) * 8;
                ra[it] = *(const short8_t*)(A  + (size_t)(m0 + row) * K + k0 + 32 + g);
                rb[it] = *(const short8_t*)(Bt + (size_t)(n0 + row) * K + k0 + 32 + g);
            }
        }
        __syncthreads();

        short8_t af[4], bfr[4];
        #pragma unroll
        for (int mt = 0; mt < 4; ++mt)
            af[mt] = *(const short8_t*)&sA[buf][wm * 64 + mt * 16 + l16][quad * 8];
        #pragma unroll
        for (int nt = 0; nt < 4; ++nt)
            bfr[nt] = *(const short8_t*)&sB[buf][wn * 64 + nt * 16 + l16][quad * 8];
        #pragma unroll
        for (int mt = 0; mt < 4; ++mt)
            #pragma unroll
            for (int nt = 0; nt < 4; ++nt)
                acc[mt][nt] = __builtin_amdgcn_mfma_f32_16x16x32_bf16(
                    af[mt], bfr[nt], acc[mt][nt], 0, 0, 0);
    }

    if (n0 < 1280) {
        float scale = (n0 < 1024) ? Q_SCALE : 1.0f;
        float sgn   = (l16 & 1) ? 1.0f : -1.0f;
        #pragma unroll
        for (int nt = 0; nt < 4; ++nt) {
            int col = n0 + wn * 64 + nt * 16 + l16;
            int ip  = (col & 63) >> 1;
            float bv = bias[col];
            #pragma unroll
            for (int mt = 0; mt < 4; ++mt) {
                #pragma unroll
                for (int r = 0; r < 4; ++r) {
                    int row = m0 + wm * 64 + mt * 16 + quad * 4 + r;
                    float v = acc[mt][nt][r] + bv;
                    float po = dpp_xor1(v);
                    float2 cs = Tab[(row & (T_SEQ - 1)) * 32 + ip];
                    float res = (v * cs.x + sgn * po * cs.y) * scale;
                    QKVb[(size_t)row * QKVW + col] = f2bs(res);
                }
            }
        }
    } else {
        __syncthreads();
        short (*sT)[136] = (short(*)[136])smem;
        #pragma unroll
        for (int nt = 0; nt < 4; ++nt) {
            int col_l = wn * 64 + nt * 16 + l16;
            float bv = bias[n0 + col_l];
            #pragma unroll
            for (int mt = 0; mt < 4; ++mt)
                #pragma unroll
                for (int r = 0; r < 4; ++r)
                    sT[col_l][wm * 64 + mt * 16 + quad * 4 + r] =
                        f2bs(acc[mt][nt][r] + bv);
        }
        __syncthreads();
        int d0 = n0 - 1280;
        #pragma unroll
        for (int it = 0; it < 8; ++it) {
            int slot = tid + 256 * it;
            int dl = slot >> 4, seg = (slot & 15) * 8;
            *(short8_t*)(Vt + (size_t)(d0 + dl) * MTOK + m0 + seg) =
                *(const short8_t*)&sT[dl][seg];
        }
    }
}

// ---------------------------------------------------------------------------
// O-projection GEMM (unchanged, fp32 out)
// ---------------------------------------------------------------------------
__global__ __launch_bounds__(256) void gemm_mfma_o(
    const short* __restrict__ A, const short* __restrict__ Bt,
    const float* __restrict__ bias, float* __restrict__ C,
    int M, int N, int K)
{
    __shared__ __align__(16) short sA[2][128][40];
    __shared__ __align__(16) short sB[2][128][40];

    int m0 = blockIdx.y * 128;
    int n0 = blockIdx.x * 128;
    int tid  = threadIdx.x;
    int w    = tid >> 6, lane = tid & 63;
    int quad = lane >> 4, l16 = lane & 15;
    int wm = w & 1, wn = w >> 1;

    f32x4 acc[4][4] = {};

    short8_t ra[2], rb[2];
    #pragma unroll
    for (int it = 0; it < 2; ++it) {
        int slot = tid + 256 * it, row = slot >> 2, g = (slot & 3) * 8;
        ra[it] = *(const short8_t*)(A  + (size_t)(m0 + row) * K + g);
        rb[it] = *(const short8_t*)(Bt + (size_t)(n0 + row) * K + g);
    }

    int buf = 0;
    for (int k0 = 0; k0 < K; k0 += 32, buf ^= 1) {
        #pragma unroll
        for (int it = 0; it < 2; ++it) {
            int slot = tid + 256 * it, row = slot >> 2, g = (slot & 3) * 8;
            *(short8_t*)&sA[buf][row][g] = ra[it];
            *(short8_t*)&sB[buf][row][g] = rb[it];
        }
        if (k0 + 32 < K) {
            #pragma unroll
            for (int it = 0; it < 2; ++it) {
                int slot = tid + 256 * it, row = slot >> 2, g = (slot & 3) * 8;
                ra[it] = *(const short8_t*)(A  + (size_t)(m0 + row) * K + k0 + 32 + g);
                rb[it] = *(const short8_t*)(Bt + (size_t)(n0 + row) * K + k0 + 32 + g);
            }
        }
        __syncthreads();

        short8_t af[4], bfr[4];
        #pragma unroll
        for (int mt = 0; mt < 4; ++mt)
            af[mt] = *(const short8_t*)&sA[buf][wm * 64 + mt * 16 + l16][quad * 8];
        #pragma unroll
        for (int nt = 0; nt < 4; ++nt)
            bfr[nt] = *(const short8_t*)&sB[buf][wn * 64 + nt * 16 + l16][quad * 8];
        #pragma unroll
        for (int mt = 0; mt < 4; ++mt)
            #pragma unroll
            for (int nt = 0; nt < 4; ++nt)
                acc[mt][nt] = __builtin_amdgcn_mfma_f32_16x16x32_bf16(
                    af[mt], bfr[nt], acc[mt][nt], 0, 0, 0);
    }

    #pragma unroll
    for (int mt = 0; mt < 4; ++mt) {
        #pragma unroll
        for (int nt = 0; nt < 4; ++nt) {
            int col = n0 + wn * 64 + nt * 16 + l16;
            float bv = bias[col];
            #pragma unroll
            for (int r = 0; r < 4; ++r) {
                int row = m0 + wm * 64 + mt * 16 + quad * 4 + r;
                C[(size_t)row * N + col] = acc[mt][nt][r] + bv;
            }
        }
    }
}

// ---------------------------------------------------------------------------
// MFMA flash attention v8 — BARRIER-FREE K-loop.
//   K A-frags and V^T B-frags load DIRECTLY from global (L2-resident),
//   eliminating all K/V LDS staging and per-chunk barriers. Block = 2 waves
//   on the SAME 32 q-rows (tiles 2u, 2u+1) of one (b,h); wave s processes
//   key-chunks of parity s (split-K flash style); one __syncthreads + LDS
//   merge of (m,l,O) at the end. LDS only: wave-private P tiles + merge buf.
//   Grid 2048 blocks x 128 thr, long-u first.
// ---------------------------------------------------------------------------
__global__ __launch_bounds__(128) void attn_mfma8(
    const short* __restrict__ QKV, const short* __restrict__ Vt,
    short* __restrict__ O)
{
    __shared__ __align__(16) short sP[2][2][16][72];   // [wave][tile][q][key]
    __shared__ __align__(16) float mO[2][64][20];      // [tile][d][q] (+pad)
    __shared__ float msh[2][16], lsh[2][16];

    const int tid  = threadIdx.x;
    const int w    = tid >> 6;          // split parity s
    const int lane = tid & 63;
    const int quad = lane >> 4;
    const int l16  = lane & 15;

    int blk = blockIdx.x;
    int u   = 63 - (blk >> 5);          // 32-row group, long first
    int bh  = blk & 31;
    int b   = bh >> 4;
    int h   = bh & 15;
    int kvh = h >> 2;
    int ct  = u >> 1;                   // last 64-key chunk index (both tiles)

    int tgA = u * 32 + l16;             // tile A q-row of this lane
    int tgB = tgA + 16;

    // Q frags (already roped + scaled by gemm_qkv epilogue)
    const short* qptrA = QKV + ((size_t)(b * T_SEQ) + tgA) * QKVW + h * HD;
    short8_t qA0 = *(const short8_t*)(qptrA + quad * 8);
    short8_t qA1 = *(const short8_t*)(qptrA + quad * 8 + 32);
    const short* qptrB = qptrA + (size_t)16 * QKVW;
    short8_t qB0 = *(const short8_t*)(qptrB + quad * 8);
    short8_t qB1 = *(const short8_t*)(qptrB + quad * 8 + 32);

    const short* kbase = QKV + (size_t)b * T_SEQ * QKVW + 1024 + kvh * HD;
    const short* vtb   = Vt + (size_t)(kvh * HD) * MTOK + b * T_SEQ;

    float mA = -INFINITY, lA = 0.f, mB = -INFINITY, lB = 0.f;
    f32x4 oA[4], oB[4];
    #pragma unroll
    for (int dt = 0; dt < 4; ++dt) {
        oA[dt] = (f32x4){0.f, 0.f, 0.f, 0.f};
        oB[dt] = (f32x4){0.f, 0.f, 0.f, 0.f};
    }

    for (int c = w; c <= ct; c += 2) {
        int j0 = c * 64;

        // ---- K fragments direct from global (8 b128 loads)
        short8_t kf[4][2];
        #pragma unroll
        for (int kt = 0; kt < 4; ++kt) {
            const short* kp = kbase + (size_t)(j0 + 16 * kt + l16) * QKVW + quad * 8;
            kf[kt][0] = *(const short8_t*)(kp);
            kf[kt][1] = *(const short8_t*)(kp + 32);
        }

        // ---- S^T for both tiles (16 MFMAs), kf shared then dead
        f32x4 sA4[4], sB4[4];
        #pragma unroll
        for (int kt = 0; kt < 4; ++kt) {
            f32x4 z = {0.f, 0.f, 0.f, 0.f};
            z = __builtin_amdgcn_mfma_f32_16x16x32_bf16(kf[kt][0], qA0, z, 0, 0, 0);
            z = __builtin_amdgcn_mfma_f32_16x16x32_bf16(kf[kt][1], qA1, z, 0, 0, 0);
            sA4[kt] = z;
            f32x4 y = {0.f, 0.f, 0.f, 0.f};
            y = __builtin_amdgcn_mfma_f32_16x16x32_bf16(kf[kt][0], qB0, y, 0, 0, 0);
            y = __builtin_amdgcn_mfma_f32_16x16x32_bf16(kf[kt][1], qB1, y, 0, 0, 0);
            sB4[kt] = y;
        }

        // ---- V^T fragments direct from global (8 b128 loads, used in PV)
        short8_t vf[4][2];
        #pragma unroll
        for (int dt = 0; dt < 4; ++dt) {
            const short* vp = vtb + (size_t)(16 * dt + l16) * MTOK + j0 + quad * 8;
            vf[dt][0] = *(const short8_t*)(vp);
            vf[dt][1] = *(const short8_t*)(vp + 32);
        }

        // ---- causal mask (owner of last chunk only)
        if (c == ct) {
            #pragma unroll
            for (int kt = 0; kt < 4; ++kt)
                #pragma unroll
                for (int r = 0; r < 4; ++r) {
                    int key = j0 + 16 * kt + quad * 4 + r;
                    if (key > tgA) sA4[kt][r] = -INFINITY;
                    if (key > tgB) sB4[kt][r] = -INFINITY;
                }
        }

        // ---- softmax tile A (per-lane q = l16)
        float alA, alB;
        {
            float vmax = sA4[0][0];
            #pragma unroll
            for (int kt = 0; kt < 4; ++kt)
                #pragma unroll
                for (int r = 0; r < 4; ++r) vmax = fmaxf(vmax, sA4[kt][r]);
            vmax = fmaxf(vmax, __shfl_xor(vmax, 16));
            vmax = fmaxf(vmax, __shfl_xor(vmax, 32));
            float mnew = fmaxf(mA, vmax);
            alA = exp2f(mA - mnew);
            mA = mnew;
            float psum = 0.f;
            #pragma unroll
            for (int kt = 0; kt < 4; ++kt) {
                short4_t pk;
                #pragma unroll
                for (int r = 0; r < 4; ++r) {
                    float p = exp2f(sA4[kt][r] - mnew);
                    psum += p;
                    pk[r] = f2bs_trunc(p);
                }
                *(short4_t*)&sP[w][0][l16][16 * kt + 4 * quad] = pk;
            }
            psum += __shfl_xor(psum, 16);
            psum += __shfl_xor(psum, 32);
            lA = lA * alA + psum;
        }
        // ---- softmax tile B
        {
            float vmax = sB4[0][0];
            #pragma unroll
            for (int kt = 0; kt < 4; ++kt)
                #pragma unroll
                for (int r = 0; r < 4; ++r) vmax = fmaxf(vmax, sB4[kt][r]);
            vmax = fmaxf(vmax, __shfl_xor(vmax, 16));
            vmax = fmaxf(vmax, __shfl_xor(vmax, 32));
            float mnew = fmaxf(mB, vmax);
            alB = exp2f(mB - mnew);
            mB = mnew;
            float psum = 0.f;
            #pragma unroll
            for (int kt = 0; kt < 4; ++kt) {
                short4_t pk;
                #pragma unroll
                for (int r = 0; r < 4; ++r) {
                    float p = exp2f(sB4[kt][r] - mnew);
                    psum += p;
                    pk[r] = f2bs_trunc(p);
                }
                *(short4_t*)&sP[w][1][l16][16 * kt + 4 * quad] = pk;
            }
            psum += __shfl_xor(psum, 16);
            psum += __shfl_xor(psum, 32);
            lB = lB * alB + psum;
        }

        // ---- rescale O when maxes changed (row-space alpha via shfl)
        if (__any(alA < 1.f)) {
            #pragma unroll
            for (int r = 0; r < 4; ++r) {
                float ar = __shfl(alA, quad * 4 + r);
                #pragma unroll
                for (int dt = 0; dt < 4; ++dt) oA[dt][r] *= ar;
            }
        }
        if (__any(alB < 1.f)) {
            #pragma unroll
            for (int r = 0; r < 4; ++r) {
                float ar = __shfl(alB, quad * 4 + r);
                #pragma unroll
                for (int dt = 0; dt < 4; ++dt) oB[dt][r] *= ar;
            }
        }

        // ---- PV (wave-local P round-trip; no barrier)
        short8_t pfA0 = *(const short8_t*)&sP[w][0][l16][quad * 8];
        short8_t pfA1 = *(const short8_t*)&sP[w][0][l16][quad * 8 + 32];
        #pragma unroll
        for (int dt = 0; dt < 4; ++dt) {
            oA[dt] = __builtin_amdgcn_mfma_f32_16x16x32_bf16(pfA0, vf[dt][0], oA[dt], 0, 0, 0);
            oA[dt] = __builtin_amdgcn_mfma_f32_16x16x32_bf16(pfA1, vf[dt][1], oA[dt], 0, 0, 0);
        }
        short8_t pfB0 = *(const short8_t*)&sP[w][1][l16][quad * 8];
        short8_t pfB1 = *(const short8_t*)&sP[w][1][l16][quad * 8 + 32];
        #pragma unroll
        for (int dt = 0; dt < 4; ++dt) {
            oB[dt] = __builtin_amdgcn_mfma_f32_16x16x32_bf16(pfB0, vf[dt][0], oB[dt], 0, 0, 0);
            oB[dt] = __builtin_amdgcn_mfma_f32_16x16x32_bf16(pfB1, vf[dt][1], oB[dt], 0, 0, 0);
        }
    }

    // ---- split merge: odd wave publishes state, even wave combines + stores
    if (w == 1) {
        #pragma unroll
        for (int dt = 0; dt < 4; ++dt) {
            *(f32x4*)&mO[0][16 * dt + l16][quad * 4] = oA[dt];
            *(f32x4*)&mO[1][16 * dt + l16][quad * 4] = oB[dt];
        }
        if (quad == 0) {
            msh[0][l16] = mA; lsh[0][l16] = lA;
            msh[1][l16] = mB; lsh[1][l16] = lB;
        }
    }
    __syncthreads();
    if (w == 0) {
        #pragma unroll
        for (int tile = 0; tile < 2; ++tile) {
            float m0 = (tile == 0) ? mA : mB;
            float l0 = (tile == 0) ? lA : lB;
            float m1 = msh[tile][l16];
            float l1 = lsh[tile][l16];
            float mstar = fmaxf(m0, m1);
            float a0 = exp2f(m0 - mstar);
            float a1 = exp2f(m1 - mstar);
            float inv = __builtin_amdgcn_rcpf(l0 * a0 + l1 * a1);
            float a0r[4], a1r[4], invr[4];
            #pragma unroll
            for (int r = 0; r < 4; ++r) {
                a0r[r]  = __shfl(a0,  quad * 4 + r);
                a1r[r]  = __shfl(a1,  quad * 4 + r);
                invr[r] = __shfl(inv, quad * 4 + r);
            }
            #pragma unroll
            for (int dt = 0; dt < 4; ++dt) {
                f32x4 ov = *(const f32x4*)&mO[tile][16 * dt + l16][quad * 4];
                f32x4 oc = (tile == 0) ? oA[dt] : oB[dt];
                #pragma unroll
                for (int r = 0; r < 4; ++r) {
                    float res = (oc[r] * a0r[r] + ov[r] * a1r[r]) * invr[r];
                    int row = u * 32 + tile * 16 + quad * 4 + r;
                    O[((size_t)b * T_SEQ + row) * C_DIM + h * HD + 16 * dt + l16] =
                        f2bs(res);
                }
            }
        }
    }
}

// ---------------------------------------------------------------------------
extern "C" void kernel_launch(void* const* d_in, const int* in_sizes, int n_in,
                              void* d_out, int out_size, void* d_ws, size_t ws_size,
                              hipStream_t stream)
{
    const float* x   = (const float*)d_in[0];
    const float* w_q = (const float*)d_in[1];
    const float* b_q = (const float*)d_in[2];
    const float* w_k = (const float*)d_in[3];
    const float* b_k = (const float*)d_in[4];
    const float* w_v = (const float*)d_in[5];
    const float* b_v = (const float*)d_in[6];
    const float* w_o = (const float*)d_in[7];
    const float* b_o = (const float*)d_in[8];
    float* out = (float*)d_out;

    char* ws = (char*)d_ws;
    short*  Xb   = (short*) (ws);                              // 8 MB
    short*  Ab   = (short*) (ws + ((size_t)8  << 20));         // 8 MB
    short*  QKVb = (short*) (ws + ((size_t)16 << 20));         // 12 MB
    short*  Wqkv = (short*) (ws + ((size_t)28 << 20));         // 3 MB
    short*  Wto  = (short*) (ws + ((size_t)31 << 20));         // 2 MB
    float*  Bqkv = (float*) (ws + ((size_t)33 << 20));         // 6 KB
    float2* Tab  = (float2*)(ws + ((size_t)33 << 20) + 8192);  // 512 KB
    short*  Vt   = (short*) (ws + ((size_t)34 << 20));         // 2 MB

    const int M = MTOK;   // 4096

    prep_kernel<<<6918, 256, 0, stream>>>(
        x, w_q, w_k, w_v, w_o, b_q, b_k, b_v, Xb, Wqkv, Wto, Bqkv, Tab);

    gemm_qkv<<<dim3(QKVW / 128, M / 128), 256, 0, stream>>>(
        Xb, Wqkv, Bqkv, Tab, QKVb, Vt);

    attn_mfma8<<<2048, 128, 0, stream>>>(QKVb, Vt, Ab);

    gemm_mfma_o<<<dim3(C_DIM / 128, M / 128), 256, 0, stream>>>(
        Ab, Wto, b_o, out, M, C_DIM, C_DIM);
}

// Round 13
// 174.928 us; speedup vs baseline: 1.1319x; 1.1319x over previous
//
#include <hip/hip_runtime.h>
#include <hip/hip_bf16.h>

typedef __hip_bfloat16 bf16;
typedef __attribute__((ext_vector_type(8))) short short8_t;
typedef __attribute__((ext_vector_type(4))) short short4_t;
typedef __attribute__((ext_vector_type(4))) float f32x4;

#define B_SZ   2
#define T_SEQ  2048
#define C_DIM  1024
#define NH     16
#define NKV    4
#define HD     64
#define QKVW   1536          // fused QKV row width (1024 Q | 256 K | 256 V)
#define MTOK   (B_SZ * T_SEQ)

#define LOG2_BASE_OVER_32 0.4152410118609203f
#define Q_SCALE 0.1803368801111204f   // 0.125 * log2(e)

__device__ __forceinline__ short f2bs(float f) {
    unsigned u = __float_as_uint(f);
    u += 0x7FFFu + ((u >> 16) & 1u);
    return (short)(u >> 16);
}
__device__ __forceinline__ short f2bs_trunc(float f) {
    return (short)(__float_as_uint(f) >> 16);
}
__device__ __forceinline__ float bs2f(short s) {
    unsigned u = ((unsigned)(unsigned short)s) << 16;
    return __uint_as_float(u);
}
// lane <-> lane^1 exchange, pure VALU (quad_perm [1,0,3,2])
__device__ __forceinline__ float dpp_xor1(float x) {
    return __int_as_float(
        __builtin_amdgcn_update_dpp(0, __float_as_int(x), 0xB1, 0xF, 0xF, true));
}

// ---------------------------------------------------------------------------
// Fused prep (unchanged): x->bf16, weight transposes, bias concat, RoPE table
// ---------------------------------------------------------------------------
__device__ __forceinline__ void transpose_tile(
    const float* __restrict__ W, short* __restrict__ Wt,
    int K, int N, int n0, int k0, int tid)
{
    __shared__ float tile[32][33];
    int tx = tid & 31, ty = tid >> 5;
    #pragma unroll
    for (int i = 0; i < 4; ++i)
        tile[ty + 8 * i][tx] = W[(size_t)(k0 + ty + 8 * i) * N + n0 + tx];
    __syncthreads();
    #pragma unroll
    for (int i = 0; i < 4; ++i)
        Wt[(size_t)(n0 + ty + 8 * i) * K + k0 + tx] = f2bs(tile[tx][ty + 8 * i]);
}

__global__ __launch_bounds__(256) void prep_kernel(
    const float* __restrict__ x,
    const float* __restrict__ w_q, const float* __restrict__ w_k,
    const float* __restrict__ w_v, const float* __restrict__ w_o,
    const float* __restrict__ b_q, const float* __restrict__ b_k,
    const float* __restrict__ b_v,
    short* __restrict__ Xb, short* __restrict__ Wqkv, short* __restrict__ Wto,
    float* __restrict__ Bqkv, float2* __restrict__ Tab)
{
    int blk = blockIdx.x, tid = threadIdx.x;
    if (blk < 4096) {
        int i = blk * 1024 + tid * 4;
        float4 v = *(const float4*)(x + i);
        short4_t o;
        o[0] = f2bs(v.x); o[1] = f2bs(v.y); o[2] = f2bs(v.z); o[3] = f2bs(v.w);
        *(short4_t*)(Xb + i) = o;
    } else if (blk < 5120) {
        int l = blk - 4096;
        transpose_tile(w_q, Wqkv, C_DIM, C_DIM, (l & 31) * 32, (l >> 5) * 32, tid);
    } else if (blk < 5376) {
        int l = blk - 5120;
        transpose_tile(w_k, Wqkv + (size_t)1024 * C_DIM, C_DIM, 256,
                       (l & 7) * 32, (l >> 3) * 32, tid);
    } else if (blk < 5632) {
        int l = blk - 5376;
        transpose_tile(w_v, Wqkv + (size_t)1280 * C_DIM, C_DIM, 256,
                       (l & 7) * 32, (l >> 3) * 32, tid);
    } else if (blk < 6656) {
        int l = blk - 5632;
        transpose_tile(w_o, Wto, C_DIM, C_DIM, (l & 31) * 32, (l >> 5) * 32, tid);
    } else if (blk < 6662) {
        int i = (blk - 6656) * 256 + tid;
        float v;
        if (i < 1024)      v = b_q[i];
        else if (i < 1280) v = b_k[i - 1024];
        else               v = b_v[i - 1280];
        Bqkv[i] = v;
    } else {
        int idx = (blk - 6662) * 256 + tid;
        int t = idx >> 5, i = idx & 31;
        float ang = (float)t * exp2f(-(float)i * LOG2_BASE_OVER_32);
        Tab[idx] = make_float2(cosf(ang), sinf(ang));
    }
}

// ---------------------------------------------------------------------------
// QKV GEMM, 128x64 tile (BM=128,BN=64,BK=32), double-buffered, 256 thr =
// 4 waves of 64x32. 768 blocks -> 3 blocks/CU. Fused epilogue:
//   n0<1024 (Q): +bias, RoPE, *Q_SCALE; 1024<=n0<1280 (K): +bias, RoPE;
//   n0>=1280 (V): +bias, transpose via LDS -> Vt[d][token].
// ---------------------------------------------------------------------------
__global__ __launch_bounds__(256) void gemm_qkv(
    const short* __restrict__ A, const short* __restrict__ Bt,
    const float* __restrict__ bias, const float2* __restrict__ Tab,
    short* __restrict__ QKVb, short* __restrict__ Vt)
{
    __shared__ __align__(16) short smem[15360];          // 30 KB
    short (*sA)[128][40] = (short(*)[128][40])smem;      // 2 x 128 x 40
    short (*sB)[64][40]  = (short(*)[64][40])(smem + 10240);

    const int K = C_DIM;
    int m0 = blockIdx.y * 128;
    int n0 = blockIdx.x * 64;
    int tid  = threadIdx.x;
    int w    = tid >> 6, lane = tid & 63;
    int quad = lane >> 4, l16 = lane & 15;
    int wm = w & 1, wn = w >> 1;

    f32x4 acc[4][2] = {};

    short8_t ra[2], rb;
    #pragma unroll
    for (int it = 0; it < 2; ++it) {
        int slot = tid + 256 * it, row = slot >> 2, g = (slot & 3) * 8;
        ra[it] = *(const short8_t*)(A + (size_t)(m0 + row) * K + g);
    }
    {
        int row = tid >> 2, g = (tid & 3) * 8;
        rb = *(const short8_t*)(Bt + (size_t)(n0 + row) * K + g);
    }

    int buf = 0;
    for (int k0 = 0; k0 < K; k0 += 32, buf ^= 1) {
        #pragma unroll
        for (int it = 0; it < 2; ++it) {
            int slot = tid + 256 * it, row = slot >> 2, g = (slot & 3) * 8;
            *(short8_t*)&sA[buf][row][g] = ra[it];
        }
        {
            int row = tid >> 2, g = (tid & 3) * 8;
            *(short8_t*)&sB[buf][row][g] = rb;
        }
        if (k0 + 32 < K) {
            #pragma unroll
            for (int it = 0; it < 2; ++it) {
                int slot = tid + 256 * it, row = slot >> 2, g = (slot & 3) * 8;
                ra[it] = *(const short8_t*)(A + (size_t)(m0 + row) * K + k0 + 32 + g);
            }
            int row = tid >> 2, g = (tid & 3) * 8;
            rb = *(const short8_t*)(Bt + (size_t)(n0 + row) * K + k0 + 32 + g);
        }
        __syncthreads();

        short8_t af[4], bfr[2];
        #pragma unroll
        for (int mt = 0; mt < 4; ++mt)
            af[mt] = *(const short8_t*)&sA[buf][wm * 64 + mt * 16 + l16][quad * 8];
        #pragma unroll
        for (int nt = 0; nt < 2; ++nt)
            bfr[nt] = *(const short8_t*)&sB[buf][wn * 32 + nt * 16 + l16][quad * 8];
        #pragma unroll
        for (int mt = 0; mt < 4; ++mt)
            #pragma unroll
            for (int nt = 0; nt < 2; ++nt)
                acc[mt][nt] = __builtin_amdgcn_mfma_f32_16x16x32_bf16(
                    af[mt], bfr[nt], acc[mt][nt], 0, 0, 0);
    }

    if (n0 < 1280) {
        // Q or K: bias + RoPE (+ Q_SCALE for Q)
        float scale = (n0 < 1024) ? Q_SCALE : 1.0f;
        float sgn   = (l16 & 1) ? 1.0f : -1.0f;
        #pragma unroll
        for (int nt = 0; nt < 2; ++nt) {
            int col = n0 + wn * 32 + nt * 16 + l16;
            int ip  = (col & 63) >> 1;
            float bv = bias[col];
            #pragma unroll
            for (int mt = 0; mt < 4; ++mt) {
                #pragma unroll
                for (int r = 0; r < 4; ++r) {
                    int row = m0 + wm * 64 + mt * 16 + quad * 4 + r;
                    float v = acc[mt][nt][r] + bv;
                    float po = dpp_xor1(v);
                    float2 cs = Tab[(row & (T_SEQ - 1)) * 32 + ip];
                    float res = (v * cs.x + sgn * po * cs.y) * scale;
                    QKVb[(size_t)row * QKVW + col] = f2bs(res);
                }
            }
        }
    } else {
        // V: bias + transpose via LDS -> Vt[d][token]
        __syncthreads();
        short (*sT)[136] = (short(*)[136])smem;    // 64 x 136 = 17.4 KB
        #pragma unroll
        for (int nt = 0; nt < 2; ++nt) {
            int col_l = wn * 32 + nt * 16 + l16;   // 0..63
            float bv = bias[n0 + col_l];
            #pragma unroll
            for (int mt = 0; mt < 4; ++mt)
                #pragma unroll
                for (int r = 0; r < 4; ++r)
                    sT[col_l][wm * 64 + mt * 16 + quad * 4 + r] =
                        f2bs(acc[mt][nt][r] + bv);
        }
        __syncthreads();
        int d0 = n0 - 1280;
        #pragma unroll
        for (int it = 0; it < 4; ++it) {
            int slot = tid + 256 * it;             // 64 dims x 16 segs
            int dl = slot >> 4, seg = (slot & 15) * 8;
            *(short8_t*)(Vt + (size_t)(d0 + dl) * MTOK + m0 + seg) =
                *(const short8_t*)&sT[dl][seg];
        }
    }
}

// ---------------------------------------------------------------------------
// O-projection GEMM, 128x64 tile (512 blocks -> 2/CU), fp32 out
// ---------------------------------------------------------------------------
__global__ __launch_bounds__(256) void gemm_mfma_o(
    const short* __restrict__ A, const short* __restrict__ Bt,
    const float* __restrict__ bias, float* __restrict__ C,
    int M, int N, int K)
{
    __shared__ __align__(16) short smem[15360];
    short (*sA)[128][40] = (short(*)[128][40])smem;
    short (*sB)[64][40]  = (short(*)[64][40])(smem + 10240);

    int m0 = blockIdx.y * 128;
    int n0 = blockIdx.x * 64;
    int tid  = threadIdx.x;
    int w    = tid >> 6, lane = tid & 63;
    int quad = lane >> 4, l16 = lane & 15;
    int wm = w & 1, wn = w >> 1;

    f32x4 acc[4][2] = {};

    short8_t ra[2], rb;
    #pragma unroll
    for (int it = 0; it < 2; ++it) {
        int slot = tid + 256 * it, row = slot >> 2, g = (slot & 3) * 8;
        ra[it] = *(const short8_t*)(A + (size_t)(m0 + row) * K + g);
    }
    {
        int row = tid >> 2, g = (tid & 3) * 8;
        rb = *(const short8_t*)(Bt + (size_t)(n0 + row) * K + g);
    }

    int buf = 0;
    for (int k0 = 0; k0 < K; k0 += 32, buf ^= 1) {
        #pragma unroll
        for (int it = 0; it < 2; ++it) {
            int slot = tid + 256 * it, row = slot >> 2, g = (slot & 3) * 8;
            *(short8_t*)&sA[buf][row][g] = ra[it];
        }
        {
            int row = tid >> 2, g = (tid & 3) * 8;
            *(short8_t*)&sB[buf][row][g] = rb;
        }
        if (k0 + 32 < K) {
            #pragma unroll
            for (int it = 0; it < 2; ++it) {
                int slot = tid + 256 * it, row = slot >> 2, g = (slot & 3) * 8;
                ra[it] = *(const short8_t*)(A + (size_t)(m0 + row) * K + k0 + 32 + g);
            }
            int row = tid >> 2, g = (tid & 3) * 8;
            rb = *(const short8_t*)(Bt + (size_t)(n0 + row) * K + k0 + 32 + g);
        }
        __syncthreads();

        short8_t af[4], bfr[2];
        #pragma unroll
        for (int mt = 0; mt < 4; ++mt)
            af[mt] = *(const short8_t*)&sA[buf][wm * 64 + mt * 16 + l16][quad * 8];
        #pragma unroll
        for (int nt = 0; nt < 2; ++nt)
            bfr[nt] = *(const short8_t*)&sB[buf][wn * 32 + nt * 16 + l16][quad * 8];
        #pragma unroll
        for (int mt = 0; mt < 4; ++mt)
            #pragma unroll
            for (int nt = 0; nt < 2; ++nt)
                acc[mt][nt] = __builtin_amdgcn_mfma_f32_16x16x32_bf16(
                    af[mt], bfr[nt], acc[mt][nt], 0, 0, 0);
    }

    #pragma unroll
    for (int mt = 0; mt < 4; ++mt) {
        #pragma unroll
        for (int nt = 0; nt < 2; ++nt) {
            int col = n0 + wn * 32 + nt * 16 + l16;
            float bv = bias[col];
            #pragma unroll
            for (int r = 0; r < 4; ++r) {
                int row = m0 + wm * 64 + mt * 16 + quad * 4 + r;
                C[(size_t)row * N + col] = acc[mt][nt][r] + bv;
            }
        }
    }
}

// ---------------------------------------------------------------------------
// MFMA flash attention v9 = r10's v6 (best measured: 55.9 us) with the rope
// prologue removed (Q arrives roped + Q_SCALEd from gemm_qkv's epilogue).
// S^T formulation, 64-key chunks, LDS staging, per-lane softmax,
// transposed b64 P writes, V from pre-transposed Vt.
// ---------------------------------------------------------------------------
__global__ __launch_bounds__(256) void attn_mfma9(
    const short* __restrict__ QKV, const short* __restrict__ Vt,
    short* __restrict__ O)
{
    __shared__ __align__(16) short sK [64][72];
    __shared__ __align__(16) short sVt[64][72];
    __shared__ __align__(16) short sP [4][16][72];

    const int tid  = threadIdx.x;
    const int w    = tid >> 6;
    const int lane = tid & 63;
    const int quad = lane >> 4;
    const int l16  = lane & 15;

    int blk = blockIdx.x;
    int grp = blk & 7;                 // (b,kvh)
    int tq  = 127 - (blk >> 3);        // long tiles first
    int kvh = grp & 3;
    int b   = grp >> 2;
    int h   = kvh * 4 + w;
    int ct  = tq >> 2;
    int tg  = tq * 16 + l16;

    // Q frags (already roped + scaled)
    const short* qptr = QKV + ((size_t)(b * T_SEQ) + tq * 16 + l16) * QKVW + h * HD;
    short8_t qf0 = *(const short8_t*)(qptr + quad * 8);
    short8_t qf1 = *(const short8_t*)(qptr + quad * 8 + 32);

    const short* kbase  = QKV + (size_t)b * T_SEQ * QKVW + 1024 + kvh * HD;
    const short* vtbase = Vt + (size_t)(kvh * HD) * MTOK + b * T_SEQ;

    float m_l = -INFINITY, l_l = 0.f;
    f32x4 oacc[4];
    #pragma unroll
    for (int dt = 0; dt < 4; ++dt) oacc[dt] = (f32x4){0.f, 0.f, 0.f, 0.f};

    const int kkey = tid >> 3, kd = (tid & 7) * 8;
    const int vdim = tid >> 3, vseg = (tid & 7) * 8;

    short8_t kr[2], vr[2];
    #pragma unroll
    for (int it = 0; it < 2; ++it) {
        kr[it] = *(const short8_t*)(kbase + (size_t)(kkey + 32 * it) * QKVW + kd);
        vr[it] = *(const short8_t*)(vtbase + (size_t)(vdim + 32 * it) * MTOK + vseg);
    }

    for (int c = 0; c <= ct; ++c) {
        __syncthreads();
        #pragma unroll
        for (int it = 0; it < 2; ++it) {
            *(short8_t*)&sK [kkey + 32 * it][kd]   = kr[it];
            *(short8_t*)&sVt[vdim + 32 * it][vseg] = vr[it];
        }
        __syncthreads();
        if (c < ct) {
            int jn = (c + 1) * 64;
            #pragma unroll
            for (int it = 0; it < 2; ++it) {
                kr[it] = *(const short8_t*)(kbase + (size_t)(jn + kkey + 32 * it) * QKVW + kd);
                vr[it] = *(const short8_t*)(vtbase + (size_t)(vdim + 32 * it) * MTOK + jn + vseg);
            }
        }

        // S^T = K Q^T : rows = keys 16kt+quad*4+r, col = q = l16
        f32x4 sacc[4];
        #pragma unroll
        for (int kt = 0; kt < 4; ++kt) {
            f32x4 z = {0.f, 0.f, 0.f, 0.f};
            short8_t kf0 = *(const short8_t*)&sK[l16 + 16 * kt][quad * 8];
            short8_t kf1 = *(const short8_t*)&sK[l16 + 16 * kt][quad * 8 + 32];
            z = __builtin_amdgcn_mfma_f32_16x16x32_bf16(kf0, qf0, z, 0, 0, 0);
            z = __builtin_amdgcn_mfma_f32_16x16x32_bf16(kf1, qf1, z, 0, 0, 0);
            sacc[kt] = z;
        }

        if (c == ct) {
            int j0 = c * 64;
            #pragma unroll
            for (int kt = 0; kt < 4; ++kt)
                #pragma unroll
                for (int r = 0; r < 4; ++r)
                    if (j0 + 16 * kt + quad * 4 + r > tg) sacc[kt][r] = -INFINITY;
        }

        float vmax = sacc[0][0];
        #pragma unroll
        for (int kt = 0; kt < 4; ++kt)
            #pragma unroll
            for (int r = 0; r < 4; ++r) vmax = fmaxf(vmax, sacc[kt][r]);
        vmax = fmaxf(vmax, __shfl_xor(vmax, 16));
        vmax = fmaxf(vmax, __shfl_xor(vmax, 32));
        float mnew = fmaxf(m_l, vmax);
        float al = exp2f(m_l - mnew);
        m_l = mnew;

        float psum = 0.f;
        #pragma unroll
        for (int kt = 0; kt < 4; ++kt) {
            short4_t pk;
            #pragma unroll
            for (int r = 0; r < 4; ++r) {
                float p = exp2f(sacc[kt][r] - mnew);
                psum += p;
                pk[r] = f2bs_trunc(p);
            }
            *(short4_t*)&sP[w][l16][16 * kt + 4 * quad] = pk;
        }
        psum += __shfl_xor(psum, 16);
        psum += __shfl_xor(psum, 32);
        l_l = l_l * al + psum;

        if (__any(al < 1.f)) {
            #pragma unroll
            for (int r = 0; r < 4; ++r) {
                float alr = __shfl(al, quad * 4 + r);
                #pragma unroll
                for (int dt = 0; dt < 4; ++dt) oacc[dt][r] *= alr;
            }
        }

        short8_t pf0 = *(const short8_t*)&sP[w][l16][quad * 8];
        short8_t pf1 = *(const short8_t*)&sP[w][l16][quad * 8 + 32];
        #pragma unroll
        for (int dt = 0; dt < 4; ++dt) {
            short8_t vf0 = *(const short8_t*)&sVt[16 * dt + l16][quad * 8];
            short8_t vf1 = *(const short8_t*)&sVt[16 * dt + l16][quad * 8 + 32];
            oacc[dt] = __builtin_amdgcn_mfma_f32_16x16x32_bf16(pf0, vf0, oacc[dt], 0, 0, 0);
            oacc[dt] = __builtin_amdgcn_mfma_f32_16x16x32_bf16(pf1, vf1, oacc[dt], 0, 0, 0);
        }
    }

    #pragma unroll
    for (int r = 0; r < 4; ++r) {
        int m = quad * 4 + r;
        float lr = __shfl(l_l, quad * 4 + r);
        float inv = __builtin_amdgcn_rcpf(lr);
        #pragma unroll
        for (int dt = 0; dt < 4; ++dt)
            O[((size_t)b * T_SEQ + tq * 16 + m) * C_DIM + h * HD + 16 * dt + l16] =
                f2bs(oacc[dt][r] * inv);
    }
}

// ---------------------------------------------------------------------------
extern "C" void kernel_launch(void* const* d_in, const int* in_sizes, int n_in,
                              void* d_out, int out_size, void* d_ws, size_t ws_size,
                              hipStream_t stream)
{
    const float* x   = (const float*)d_in[0];
    const float* w_q = (const float*)d_in[1];
    const float* b_q = (const float*)d_in[2];
    const float* w_k = (const float*)d_in[3];
    const float* b_k = (const float*)d_in[4];
    const float* w_v = (const float*)d_in[5];
    const float* b_v = (const float*)d_in[6];
    const float* w_o = (const float*)d_in[7];
    const float* b_o = (const float*)d_in[8];
    float* out = (float*)d_out;

    char* ws = (char*)d_ws;
    short*  Xb   = (short*) (ws);                              // 8 MB
    short*  Ab   = (short*) (ws + ((size_t)8  << 20));         // 8 MB
    short*  QKVb = (short*) (ws + ((size_t)16 << 20));         // 12 MB
    short*  Wqkv = (short*) (ws + ((size_t)28 << 20));         // 3 MB
    short*  Wto  = (short*) (ws + ((size_t)31 << 20));         // 2 MB
    float*  Bqkv = (float*) (ws + ((size_t)33 << 20));         // 6 KB
    float2* Tab  = (float2*)(ws + ((size_t)33 << 20) + 8192);  // 512 KB
    short*  Vt   = (short*) (ws + ((size_t)34 << 20));         // 2 MB

    const int M = MTOK;   // 4096

    prep_kernel<<<6918, 256, 0, stream>>>(
        x, w_q, w_k, w_v, w_o, b_q, b_k, b_v, Xb, Wqkv, Wto, Bqkv, Tab);

    gemm_qkv<<<dim3(QKVW / 64, M / 128), 256, 0, stream>>>(
        Xb, Wqkv, Bqkv, Tab, QKVb, Vt);

    attn_mfma9<<<B_SZ * NKV * 128, 256, 0, stream>>>(QKVb, Vt, Ab);

    gemm_mfma_o<<<dim3(C_DIM / 64, M / 128), 256, 0, stream>>>(
        Ab, Wto, b_o, out, M, C_DIM, C_DIM);
}